// Round 1
// baseline (1116.790 us; speedup 1.0000x reference)
//
#include <hip/hip_runtime.h>

// st_attention_block: N=256, C=64, T=128, V=25, O=64, R=4
// ws layout (floats): S[N][64][25] @ 0 (409600), att[N][625][64] @ 409600 (10240000)
// Total ws use: ~42.6 MB.

// ---------------- Kernel A: temporal sum S[n,c,v] = sum_t x[n,c,t,v] ----------------
// Per (n,c): 3200 floats = 800 aligned float4. Thread i0 (0..24) reads float4s at
// i0 + 25k (k<32): element j of each float4 always lands in bin (4*i0+j) % 25,
// so bins stay in registers; regroup 100 partials -> 25 bins via LDS.
__global__ __launch_bounds__(256) void kA_tsum(const float* __restrict__ x,
                                               float* __restrict__ S) {
  __shared__ float part[8 * 25 * 4];
  int b = blockIdx.x;
  int n = b >> 3, cg = b & 7;      // 8 c-groups of 8
  int tid = threadIdx.x;
  if (tid < 200) {
    int cl = tid / 25, i0 = tid % 25;
    int c = cg * 8 + cl;
    const float4* p = (const float4*)(x + (size_t)(n * 64 + c) * 3200);
    float4 acc = {0.f, 0.f, 0.f, 0.f};
#pragma unroll 8
    for (int k = 0; k < 32; ++k) {
      float4 t = p[i0 + 25 * k];
      acc.x += t.x; acc.y += t.y; acc.z += t.z; acc.w += t.w;
    }
    float* pp = &part[(cl * 25 + i0) * 4];
    pp[0] = acc.x; pp[1] = acc.y; pp[2] = acc.z; pp[3] = acc.w;
  }
  __syncthreads();
  if (tid < 200) {
    int cl = tid / 25, bin = tid % 25;
    float s = 0.f;
#pragma unroll
    for (int j = 0; j < 4; ++j) {
      int i0 = ((bin - j + 25) * 19) % 25;   // inv(4) mod 25 = 19
      s += part[(cl * 25 + i0) * 4 + j];
    }
    int c = cg * 8 + cl;
    S[(size_t)(n * 64 + c) * 25 + bin] = s;
  }
}

// ---------------- Kernel B: per-n attention matrix ----------------
// k,q from S; x1=k*q, x2=k-q; conv1/conv2 (4x4); tanh; ffn (64x8); +adjc.
// att stored [n][v*25+u][o] (o fastest) so kB stores and kC loads are coalesced.
__global__ __launch_bounds__(256) void kB_att(
    const float* __restrict__ S,
    const float* __restrict__ Wk_w, const float* __restrict__ Wk_b,
    const float* __restrict__ Wq_w, const float* __restrict__ Wq_b,
    const float* __restrict__ conv1_w, const float* __restrict__ conv1_b,
    const float* __restrict__ conv2_w, const float* __restrict__ conv2_b,
    const float* __restrict__ ffn_w, const float* __restrict__ ffn_b,
    const float* __restrict__ alpha, const float* __restrict__ adjc,
    float* __restrict__ att) {
  __shared__ float S_l[1600];
  __shared__ float kq_l[2][4][25];
  __shared__ float a_l[8][640];
  __shared__ float ffnT[8][64];
  int n = blockIdx.x, tid = threadIdx.x;
  for (int i = tid; i < 1600; i += 256) S_l[i] = S[(size_t)n * 1600 + i];
  for (int i = tid; i < 512; i += 256) {
    int r = i >> 6, o = i & 63;
    ffnT[r][o] = ffn_w[o * 8 + r];
  }
  __syncthreads();
  if (tid < 200) {                         // k (tid<100) and q (tid>=100)
    int which = tid / 100;
    int rr = tid % 100;
    int r = rr / 25, v = rr % 25;
    const float* W = which ? Wq_w : Wk_w;
    float s = 0.f;
    for (int c = 0; c < 64; ++c) s += W[r * 64 + c] * S_l[c * 25 + v];
    kq_l[which][r][v] = s * (1.0f / 128.0f) + (which ? Wq_b[r] : Wk_b[r]);
  }
  __syncthreads();
  for (int vu = tid; vu < 625; vu += 256) {
    int v = vu / 25, u = vu % 25;
    float kk[4], qq[4];
#pragma unroll
    for (int r = 0; r < 4; ++r) { kk[r] = kq_l[0][r][v]; qq[r] = kq_l[1][r][u]; }
#pragma unroll
    for (int s = 0; s < 4; ++s) {
      float t1 = conv1_b[s], t2 = conv2_b[s];
#pragma unroll
      for (int r = 0; r < 4; ++r) {
        t1 += conv1_w[s * 4 + r] * (kk[r] * qq[r]);
        t2 += conv2_w[s * 4 + r] * (kk[r] - qq[r]);
      }
      a_l[s][vu]     = tanhf(t1);
      a_l[s + 4][vu] = tanhf(t2);
    }
  }
  __syncthreads();
  float alpha0 = alpha[0];
  int o = tid & 63, vu0 = tid >> 6;
  for (int vu = vu0; vu < 625; vu += 4) {
    float s = ffn_b[o];
#pragma unroll
    for (int r = 0; r < 8; ++r) s += ffnT[r][o] * a_l[r][vu];
    int v = vu / 25, u = vu - v * 25;
    att[((size_t)n * 625 + vu) * 64 + o] = alpha0 * s + adjc[v * 25 + u];
  }
}

// ---------------- Kernel C: fused v-projection + att@v ----------------
// Block = (n, 8-t tile). Thread = (o = tid&63, tg = tid>>6) owns t = tg*2, tg*2+1.
// Phase 1: v[2][25] regs = Wv . x-tile (x staged in LDS in 2 c-chunks; xt reads
// are wave-uniform broadcasts; Wv read lane-o-consecutive -> conflict-free).
// Phase 2: out = att . v, att loads coalesced 256B (lane=o), result staged in
// 65-padded LDS transpose -> fully coalesced global store.
__global__ __launch_bounds__(256, 3) void kC_out(
    const float* __restrict__ x, const float* __restrict__ Wv_w,
    const float* __restrict__ Wv_b, const float* __restrict__ att,
    float* __restrict__ out) {
  __shared__ __align__(16) float smem[13000];   // 52000 B
  float* Wv_s = smem;          // phase1: [c][o] = [64][64]
  float* xt   = smem + 4096;   // phase1: [32][8][28] (rows 112B -> 16B aligned)
  int bidx = blockIdx.x;
  int n = bidx >> 4, tc = bidx & 15;
  int t0 = tc * 8;
  int tid = threadIdx.x;
  int o = tid & 63, tg = tid >> 6;

  // stage WvT (coalesced global read; one-time conflicted LDS write is cheap)
  for (int i = tid; i < 4096; i += 256) {
    int oo = i >> 6, c = i & 63;
    Wv_s[c * 64 + oo] = Wv_w[i];
  }
  float bo = Wv_b[o];
  float vacc[2][25];
#pragma unroll
  for (int u = 0; u < 25; ++u) { vacc[0][u] = bo; vacc[1][u] = bo; }

  size_t base_x = (size_t)n * 204800 + (size_t)t0 * 25;
  for (int cc = 0; cc < 64; cc += 32) {
    __syncthreads();
    for (int i = tid; i < 6400; i += 256) {     // stage x[cc..cc+31][t0..t0+7][*]
      int cl = i / 200, rr = i % 200;
      int tt = rr / 25, u = rr % 25;
      xt[(cl * 8 + tt) * 28 + u] = x[base_x + (size_t)(cc + cl) * 3200 + rr];
    }
    __syncthreads();
    for (int cl = 0; cl < 32; ++cl) {
      float w = Wv_s[(cc + cl) * 64 + o];
      const float* xr0 = &xt[(cl * 8 + tg * 2) * 28];
#pragma unroll
      for (int u = 0; u < 25; ++u) {
        vacc[0][u] += w * xr0[u];
        vacc[1][u] += w * xr0[28 + u];
      }
    }
  }
  __syncthreads();

  // phase 2: out[o][t][vout] = sum_u att[n][vout*25+u][o] * v[t][u]
  float* outl = smem;                       // [tv=200][65] padded transpose
  const float* attn = att + (size_t)n * 40000 + o;
  int tb = tg * 2 * 25;
  for (int vout = 0; vout < 25; ++vout) {
    const float* ar = attn + vout * 1600;
    float s0 = 0.f, s1 = 0.f;
#pragma unroll
    for (int u = 0; u < 25; ++u) {
      float a = ar[(size_t)u * 64];
      s0 += a * vacc[0][u];
      s1 += a * vacc[1][u];
    }
    outl[(tb + vout) * 65 + o]      = s0;
    outl[(tb + 25 + vout) * 65 + o] = s1;
  }
  __syncthreads();
  size_t base_o = (size_t)n * 204800 + (size_t)t0 * 25;
  for (int i = tid; i < 12800; i += 256) {
    int oo = i / 200, tv = i % 200;
    out[base_o + (size_t)oo * 3200 + tv] = outl[tv * 65 + oo];
  }
}

extern "C" void kernel_launch(void* const* d_in, const int* in_sizes, int n_in,
                              void* d_out, int out_size, void* d_ws, size_t ws_size,
                              hipStream_t stream) {
  const float* x       = (const float*)d_in[0];
  const float* adjc    = (const float*)d_in[1];
  const float* Wk_w    = (const float*)d_in[2];
  const float* Wk_b    = (const float*)d_in[3];
  const float* Wq_w    = (const float*)d_in[4];
  const float* Wq_b    = (const float*)d_in[5];
  const float* Wv_w    = (const float*)d_in[6];
  const float* Wv_b    = (const float*)d_in[7];
  const float* conv1_w = (const float*)d_in[8];
  const float* conv1_b = (const float*)d_in[9];
  const float* conv2_w = (const float*)d_in[10];
  const float* conv2_b = (const float*)d_in[11];
  const float* ffn_w   = (const float*)d_in[12];
  const float* ffn_b   = (const float*)d_in[13];
  const float* alpha   = (const float*)d_in[14];
  float* outp = (float*)d_out;
  float* S    = (float*)d_ws;
  float* att  = S + 409600;

  kA_tsum<<<2048, 256, 0, stream>>>(x, S);
  kB_att<<<256, 256, 0, stream>>>(S, Wk_w, Wk_b, Wq_w, Wq_b, conv1_w, conv1_b,
                                  conv2_w, conv2_b, ffn_w, ffn_b, alpha, adjc, att);
  kC_out<<<4096, 256, 0, stream>>>(x, Wv_w, Wv_b, att, outp);
}

// Round 2
// 621.767 us; speedup vs baseline: 1.7962x; 1.7962x over previous
//
#include <hip/hip_runtime.h>

// st_attention_block: N=256, C=64, T=128, V=25, O=64, R=4
// ws layout (floats): S[N][64][25] @ 0 (409600), att[N][625][64] @ 409600 (10240000)

// ---------------- Kernel A: temporal sum S[n,c,v] = sum_t x[n,c,t,v] ----------------
__global__ __launch_bounds__(256) void kA_tsum(const float* __restrict__ x,
                                               float* __restrict__ S) {
  __shared__ float part[8 * 25 * 4];
  int b = blockIdx.x;
  int n = b >> 3, cg = b & 7;      // 8 c-groups of 8
  int tid = threadIdx.x;
  if (tid < 200) {
    int cl = tid / 25, i0 = tid % 25;
    int c = cg * 8 + cl;
    const float4* p = (const float4*)(x + (size_t)(n * 64 + c) * 3200);
    float4 acc = {0.f, 0.f, 0.f, 0.f};
#pragma unroll 8
    for (int k = 0; k < 32; ++k) {
      float4 t = p[i0 + 25 * k];
      acc.x += t.x; acc.y += t.y; acc.z += t.z; acc.w += t.w;
    }
    float* pp = &part[(cl * 25 + i0) * 4];
    pp[0] = acc.x; pp[1] = acc.y; pp[2] = acc.z; pp[3] = acc.w;
  }
  __syncthreads();
  if (tid < 200) {
    int cl = tid / 25, bin = tid % 25;
    float s = 0.f;
#pragma unroll
    for (int j = 0; j < 4; ++j) {
      int i0 = ((bin - j + 25) * 19) % 25;   // inv(4) mod 25 = 19
      s += part[(cl * 25 + i0) * 4 + j];
    }
    int c = cg * 8 + cl;
    S[(size_t)(n * 64 + c) * 25 + bin] = s;
  }
}

// ---------------- Kernel B: per-n attention matrix ----------------
__global__ __launch_bounds__(256) void kB_att(
    const float* __restrict__ S,
    const float* __restrict__ Wk_w, const float* __restrict__ Wk_b,
    const float* __restrict__ Wq_w, const float* __restrict__ Wq_b,
    const float* __restrict__ conv1_w, const float* __restrict__ conv1_b,
    const float* __restrict__ conv2_w, const float* __restrict__ conv2_b,
    const float* __restrict__ ffn_w, const float* __restrict__ ffn_b,
    const float* __restrict__ alpha, const float* __restrict__ adjc,
    float* __restrict__ att) {
  __shared__ float S_l[1600];
  __shared__ float kq_l[2][4][25];
  __shared__ float a_l[8][640];
  __shared__ float ffnT[8][64];
  int n = blockIdx.x, tid = threadIdx.x;
  for (int i = tid; i < 1600; i += 256) S_l[i] = S[(size_t)n * 1600 + i];
  for (int i = tid; i < 512; i += 256) {
    int r = i >> 6, o = i & 63;
    ffnT[r][o] = ffn_w[o * 8 + r];
  }
  __syncthreads();
  if (tid < 200) {                         // k (tid<100) and q (tid>=100)
    int which = tid / 100;
    int rr = tid % 100;
    int r = rr / 25, v = rr % 25;
    const float* W = which ? Wq_w : Wk_w;
    float s = 0.f;
    for (int c = 0; c < 64; ++c) s += W[r * 64 + c] * S_l[c * 25 + v];
    kq_l[which][r][v] = s * (1.0f / 128.0f) + (which ? Wq_b[r] : Wk_b[r]);
  }
  __syncthreads();
  for (int vu = tid; vu < 625; vu += 256) {
    int v = vu / 25, u = vu % 25;
    float kk[4], qq[4];
#pragma unroll
    for (int r = 0; r < 4; ++r) { kk[r] = kq_l[0][r][v]; qq[r] = kq_l[1][r][u]; }
#pragma unroll
    for (int s = 0; s < 4; ++s) {
      float t1 = conv1_b[s], t2 = conv2_b[s];
#pragma unroll
      for (int r = 0; r < 4; ++r) {
        t1 += conv1_w[s * 4 + r] * (kk[r] * qq[r]);
        t2 += conv2_w[s * 4 + r] * (kk[r] - qq[r]);
      }
      a_l[s][vu]     = tanhf(t1);
      a_l[s + 4][vu] = tanhf(t2);
    }
  }
  __syncthreads();
  float alpha0 = alpha[0];
  int o = tid & 63, vu0 = tid >> 6;
  for (int vu = vu0; vu < 625; vu += 4) {
    float s = ffn_b[o];
#pragma unroll
    for (int r = 0; r < 8; ++r) s += ffnT[r][o] * a_l[r][vu];
    int v = vu / 25, u = vu - v * 25;
    att[((size_t)n * 625 + vu) * 64 + o] = alpha0 * s + adjc[v * 25 + u];
  }
}

// ---------------- Kernel C: fused v-projection + att@v ----------------
// Block = (n, 8-t tile). Phase 1 thread = (og = tid&31 -> o in {og, og+32},
// tt = tid>>5 -> t = t0+tt): per c reads 2 w + one x-row via b128 (9 LDS instrs
// per 50 FMA). Then one shfl_xor(32) per u swaps the (2o x 1t) tile into
// (1o x 2t) with lane == o, so phase 2 (att loads coalesced over lane=o) and
// the padded-LDS output transpose run with zero extra LDS traffic.
__global__ __launch_bounds__(256, 3) void kC_out(
    const float* __restrict__ x, const float* __restrict__ Wv_w,
    const float* __restrict__ Wv_b, const float* __restrict__ att,
    float* __restrict__ out) {
  __shared__ __align__(16) float smem[13000];   // 52000 B
  float* Wv_s = smem;          // phase1: [c][o] = [64][64]
  float* xt   = smem + 4096;   // phase1: [32 c][8 t][28] (112B rows, 16B aligned)
  int bidx = blockIdx.x;
  int n = bidx >> 4, tc = bidx & 15;
  int t0 = tc * 8;
  int tid = threadIdx.x;
  int og = tid & 31;           // o-pair id: o in {og, og+32}
  int tt = tid >> 5;           // t index 0..7
  int ttp = tt & 1;            // parity within wave

  for (int i = tid; i < 4096; i += 256) {       // stage Wv^T: Wv_s[c][o]
    int oo = i >> 6, c = i & 63;
    Wv_s[c * 64 + oo] = Wv_w[i];
  }
  float acc0[25], acc1[25];
  {
    float b0 = Wv_b[og], b1 = Wv_b[og + 32];
#pragma unroll
    for (int u = 0; u < 25; ++u) { acc0[u] = b0; acc1[u] = b1; }
  }

  size_t base_x = (size_t)n * 204800 + (size_t)t0 * 25;
  for (int cc = 0; cc < 64; cc += 32) {
    __syncthreads();
    for (int i = tid; i < 6400; i += 256) {     // stage x[cc..cc+31][t0..t0+7][*]
      int cl = i / 200, rr = i % 200;
      int ts = rr / 25, u = rr % 25;
      xt[(cl * 8 + ts) * 28 + u] = x[base_x + (size_t)(cc + cl) * 3200 + rr];
    }
    __syncthreads();
    for (int cl = 0; cl < 32; ++cl) {
      float w0 = Wv_s[(cc + cl) * 64 + og];
      float w1 = Wv_s[(cc + cl) * 64 + og + 32];
      const float4* xr4 = (const float4*)&xt[(cl * 8 + tt) * 28];
      float4 X0 = xr4[0], X1 = xr4[1], X2 = xr4[2];
      float4 X3 = xr4[3], X4 = xr4[4], X5 = xr4[5];
      float x24 = ((const float*)xr4)[24];
      float xv[25] = {X0.x, X0.y, X0.z, X0.w, X1.x, X1.y, X1.z, X1.w,
                      X2.x, X2.y, X2.z, X2.w, X3.x, X3.y, X3.z, X3.w,
                      X4.x, X4.y, X4.z, X4.w, X5.x, X5.y, X5.z, X5.w, x24};
#pragma unroll
      for (int u = 0; u < 25; ++u) {
        acc0[u] += w0 * xv[u];
        acc1[u] += w1 * xv[u];
      }
    }
  }

  // In-wave transpose: (2 o, 1 t) -> (1 o, 2 t); resulting lane index == o.
  float vA[25], vB[25];
#pragma unroll
  for (int u = 0; u < 25; ++u) {
    float sent = ttp ? acc0[u] : acc1[u];
    float got = __shfl_xor(sent, 32);
    vA[u] = ttp ? got : acc0[u];   // t = t0 + 2*wave
    vB[u] = ttp ? acc1[u] : got;   // t = t0 + 2*wave + 1
  }
  __syncthreads();

  // phase 2: out[o][t][vout] = sum_u att[n][vout*25+u][o] * v[t][u]
  int o = tid & 63;                // == og + 32*ttp
  int tw = tid >> 6;               // wave id -> t-pair (t0+2tw, t0+2tw+1)
  float* outl = smem;              // [tv=200][65] padded transpose
  const float* attn = att + (size_t)n * 40000 + o;
  int tb = tw * 50;
  for (int vout = 0; vout < 25; ++vout) {
    const float* ar = attn + vout * 1600;
    float s0 = 0.f, s1 = 0.f;
#pragma unroll
    for (int u = 0; u < 25; ++u) {
      float a = ar[(size_t)u * 64];
      s0 += a * vA[u];
      s1 += a * vB[u];
    }
    outl[(tb + vout) * 65 + o]      = s0;
    outl[(tb + 25 + vout) * 65 + o] = s1;
  }
  __syncthreads();
  size_t base_o = (size_t)n * 204800 + (size_t)t0 * 25;
  for (int i = tid; i < 12800; i += 256) {
    int oo = i / 200, tv = i % 200;
    out[base_o + (size_t)oo * 3200 + tv] = outl[tv * 65 + oo];
  }
}

extern "C" void kernel_launch(void* const* d_in, const int* in_sizes, int n_in,
                              void* d_out, int out_size, void* d_ws, size_t ws_size,
                              hipStream_t stream) {
  const float* x       = (const float*)d_in[0];
  const float* adjc    = (const float*)d_in[1];
  const float* Wk_w    = (const float*)d_in[2];
  const float* Wk_b    = (const float*)d_in[3];
  const float* Wq_w    = (const float*)d_in[4];
  const float* Wq_b    = (const float*)d_in[5];
  const float* Wv_w    = (const float*)d_in[6];
  const float* Wv_b    = (const float*)d_in[7];
  const float* conv1_w = (const float*)d_in[8];
  const float* conv1_b = (const float*)d_in[9];
  const float* conv2_w = (const float*)d_in[10];
  const float* conv2_b = (const float*)d_in[11];
  const float* ffn_w   = (const float*)d_in[12];
  const float* ffn_b   = (const float*)d_in[13];
  const float* alpha   = (const float*)d_in[14];
  float* outp = (float*)d_out;
  float* S    = (float*)d_ws;
  float* att  = S + 409600;

  kA_tsum<<<2048, 256, 0, stream>>>(x, S);
  kB_att<<<256, 256, 0, stream>>>(S, Wk_w, Wk_b, Wq_w, Wq_b, conv1_w, conv1_b,
                                  conv2_w, conv2_b, ffn_w, ffn_b, alpha, adjc, att);
  kC_out<<<4096, 256, 0, stream>>>(x, Wv_w, Wv_b, att, outp);
}